// Round 6
// baseline (4433.095 us; speedup 1.0000x reference)
//
#include <hip/hip_runtime.h>

#define N_NODES   100000
#define N_EDGES   1600000
#define F         128
#define N_CLASSES 47

#define NB        782                 // dst buckets of 128 nodes
#define NCH       13                  // src chunks of 8192 nodes (2 MB bf16 each)
#define M_CELLS   (NB * NCH * 8)      // 81328 (x8 xcd sub-ranges)
#define SCANV_B   80                  // ceil(M_CELLS / 1024)
#define NEB       6250                // ceil(N_EDGES / 256)

typedef unsigned int uint32;

typedef short  v8s __attribute__((ext_vector_type(8)));   // 8 x bf16 (MFMA A/B frag)
typedef float  v4f __attribute__((ext_vector_type(4)));   // MFMA C/D frag

// bf16 helpers (RNE)
__device__ __forceinline__ uint32 f2bf(float f) {
    uint32 u = __float_as_uint(f);
    return (u + 0x7FFFu + ((u >> 16) & 1u)) >> 16;
}
__device__ __forceinline__ float bfl(uint32 u) { return __uint_as_float(u << 16); }
__device__ __forceinline__ float bfh(uint32 u) { return __uint_as_float(u & 0xFFFF0000u); }

// ---------------- edge histogram + degree count ----------------
// cell = (dst>>7)*NCH + (src>>13); k = cell*8 + (blockIdx&7)  [xcd heuristic]

__global__ void histcnt_kernel(const int* __restrict__ dst, const int* __restrict__ src,
                               int* __restrict__ cnt, int* __restrict__ hist) {
    int e = blockIdx.x * 256 + threadIdx.x;
    if (e < N_EDGES) {
        int d = dst[e], s = src[e];
        atomicAdd(&cnt[d], 1);
        int k = ((((d >> 7) * NCH) + (s >> 13)) << 3) | (blockIdx.x & 7);
        atomicAdd(&hist[k], 1);
    }
}

// ---------------- hierarchical exclusive scan over M_CELLS ----------------

__global__ void scanA_kernel(const int* __restrict__ hist, int* __restrict__ blk_sums) {
    __shared__ int red[1024];
    int t = threadIdx.x;
    int i = blockIdx.x * 1024 + t;
    red[t] = (i < M_CELLS) ? hist[i] : 0;
    __syncthreads();
    #pragma unroll
    for (int off = 512; off > 0; off >>= 1) {
        if (t < off) red[t] += red[t + off];
        __syncthreads();
    }
    if (t == 0) blk_sums[blockIdx.x] = red[0];
}

__global__ void scanB_kernel(int* __restrict__ blk_sums, int* __restrict__ offs) {
    __shared__ int s[128];
    int t = threadIdx.x;
    int v = (t < SCANV_B) ? blk_sums[t] : 0;
    s[t] = v;
    __syncthreads();
    #pragma unroll
    for (int off = 1; off < 128; off <<= 1) {
        int add = (t >= off) ? s[t - off] : 0;
        __syncthreads();
        s[t] += add;
        __syncthreads();
    }
    if (t < SCANV_B) blk_sums[t] = s[t] - v;   // exclusive block offset
    if (t == 0) offs[M_CELLS] = N_EDGES;       // sentinel for last cell's end
}

__global__ void scanC_kernel(const int* __restrict__ hist, const int* __restrict__ blk_offs,
                             int* __restrict__ offs, int* __restrict__ cursor) {
    __shared__ int s[1024];
    int t = threadIdx.x;
    int i = blockIdx.x * 1024 + t;
    int c = (i < M_CELLS) ? hist[i] : 0;
    s[t] = c;
    __syncthreads();
    #pragma unroll
    for (int off = 1; off < 1024; off <<= 1) {
        int add = (t >= off) ? s[t - off] : 0;
        __syncthreads();
        s[t] += add;
        __syncthreads();
    }
    if (i < M_CELLS) {
        int e = s[t] - c + blk_offs[blockIdx.x];
        offs[i]   = e;
        cursor[i] = e;
    }
}

// ---------------- scatter: edges -> cell-sorted packed pairs ----------------
// pair = (dst&127)<<17 | src   (7 + 17 bits)

__global__ void scatter_kernel(const int* __restrict__ dst, const int* __restrict__ src,
                               int* __restrict__ cursor, uint32* __restrict__ pair) {
    int e = blockIdx.x * 256 + threadIdx.x;
    if (e < N_EDGES) {
        int d = dst[e], s = src[e];
        int k = ((((d >> 7) * NCH) + (s >> 13)) << 3) | (blockIdx.x & 7);
        int pos = atomicAdd(&cursor[k], 1);
        pair[pos] = ((uint32)(d & 127) << 17) | (uint32)s;
    }
}

// ---------------- weight pre-pack: fp32 Wn/Ws -> bf16 MFMA A-frags ----------------

__global__ void pack_w_kernel(const float* __restrict__ Wn, const float* __restrict__ Ws,
                              int nout, unsigned short* __restrict__ wfrag) {
    int tile = blockIdx.x;           // mt*8 + kt
    int kt   = tile & 7;
    int mt   = tile >> 3;
    int lane = threadIdx.x;          // 64
    int quad = lane >> 4;
    int m    = mt * 16 + (lane & 15);
    uint32 packed[4];
    #pragma unroll
    for (int jj = 0; jj < 4; ++jj) {
        uint32 lo = 0, hi = 0;
        #pragma unroll
        for (int b = 0; b < 2; ++b) {
            int j = jj * 2 + b;
            int k = kt * 32 + quad * 8 + j;
            float w = 0.f;
            if (m < nout) w = (k < F) ? Wn[(size_t)k * nout + m] : Ws[(size_t)(k - F) * nout + m];
            if (b == 0) lo = f2bf(w); else hi = f2bf(w);
        }
        packed[jj] = lo | (hi << 16);
    }
    uint4 o = make_uint4(packed[0], packed[1], packed[2], packed[3]);
    *(uint4*)(wfrag + ((size_t)tile * 64 + lane) * 8) = o;
}

// ---------------- embedding gather: fp32 embed -> bf16 h ----------------

__global__ void gather_embed_kernel(const float* __restrict__ embed,
                                    const int* __restrict__ idx,
                                    unsigned short* __restrict__ h) {
    int i = blockIdx.x * blockDim.x + threadIdx.x;
    const int TOTAL = N_NODES * (F / 4);
    if (i < TOTAL) {
        int node = i >> 5;
        int c4 = i & 31;
        float4 v = ((const float4*)(embed + (size_t)idx[node] * F))[c4];
        uint2 o;
        o.x = f2bf(v.x) | (f2bf(v.y) << 16);
        o.y = f2bf(v.z) | (f2bf(v.w) << 16);
        ((uint2*)(h + (size_t)node * F))[c4] = o;
    }
}

// ---------------- cache-blocked push aggregation ----------------
// one block per 128-node dst bucket; 64 KB LDS fp32 accumulator.
// iterates src-chunks in identical order across all blocks -> each 2 MB
// h-chunk is L2-resident chip-wide during its sweep.

__global__ __launch_bounds__(512)
void agg_push_kernel(const unsigned short* __restrict__ h,
                     const uint32* __restrict__ pair,
                     const int* __restrict__ offs,
                     const int* __restrict__ cnt,
                     unsigned short* __restrict__ mean) {
    __shared__ float acc[128 * 128];
    const int tid = threadIdx.x;

    float4* af4 = (float4*)acc;
    #pragma unroll
    for (int i = 0; i < 8; ++i) af4[tid + i * 512] = make_float4(0.f, 0.f, 0.f, 0.f);
    __syncthreads();

    const int b    = blockIdx.x;
    const int wave = tid >> 6;
    const int lane = tid & 63;
    const int l2   = lane * 2;
    const uint32* hp = (const uint32*)h;   // 64 uints per node row

    for (int c = 0; c < NCH; ++c) {
        const int cell = b * NCH + c;
        const int beg = offs[cell << 3];
        const int end = offs[(cell + 1) << 3];
        int p = beg + wave * 4;
        for (; p + 4 <= end; p += 32) {
            uint32 w0 = pair[p], w1 = pair[p + 1], w2 = pair[p + 2], w3 = pair[p + 3];
            uint32 x0 = hp[(size_t)(w0 & 0x1FFFFu) * 64 + lane];
            uint32 x1 = hp[(size_t)(w1 & 0x1FFFFu) * 64 + lane];
            uint32 x2 = hp[(size_t)(w2 & 0x1FFFFu) * 64 + lane];
            uint32 x3 = hp[(size_t)(w3 & 0x1FFFFu) * 64 + lane];
            atomicAdd(&acc[(w0 >> 17) * 128 + l2],     bfl(x0));
            atomicAdd(&acc[(w0 >> 17) * 128 + l2 + 1], bfh(x0));
            atomicAdd(&acc[(w1 >> 17) * 128 + l2],     bfl(x1));
            atomicAdd(&acc[(w1 >> 17) * 128 + l2 + 1], bfh(x1));
            atomicAdd(&acc[(w2 >> 17) * 128 + l2],     bfl(x2));
            atomicAdd(&acc[(w2 >> 17) * 128 + l2 + 1], bfh(x2));
            atomicAdd(&acc[(w3 >> 17) * 128 + l2],     bfl(x3));
            atomicAdd(&acc[(w3 >> 17) * 128 + l2 + 1], bfh(x3));
        }
        #pragma unroll
        for (int i = 0; i < 4; ++i) {     // tail: at most one wave partial
            if (p + i < end) {
                uint32 w = pair[p + i];
                uint32 x = hp[(size_t)(w & 0x1FFFFu) * 64 + lane];
                atomicAdd(&acc[(w >> 17) * 128 + l2],     bfl(x));
                atomicAdd(&acc[(w >> 17) * 128 + l2 + 1], bfh(x));
            }
        }
    }
    __syncthreads();

    // write means: 4 threads per node, 32 feats each (bf16-packed, coalesced)
    const int nl = tid >> 2;
    const int q  = tid & 3;
    const int v  = b * 128 + nl;
    if (v < N_NODES) {
        float r = 1.0f / (float)max(cnt[v], 1);
        const float* arow = &acc[nl * 128 + q * 32];
        uint32* mrow = (uint32*)mean + (size_t)v * 64 + q * 16;
        #pragma unroll
        for (int j = 0; j < 4; ++j) {
            uint4 o;
            o.x = f2bf(arow[j*8+0]*r) | (f2bf(arow[j*8+1]*r) << 16);
            o.y = f2bf(arow[j*8+2]*r) | (f2bf(arow[j*8+3]*r) << 16);
            o.z = f2bf(arow[j*8+4]*r) | (f2bf(arow[j*8+5]*r) << 16);
            o.w = f2bf(arow[j*8+6]*r) | (f2bf(arow[j*8+7]*r) << 16);
            *(uint4*)(mrow + j * 4) = o;
        }
    }
}

// ---------------- MFMA GEMM: out = [mean|h] @ Wcat + b (+relu) ----------------

template<int MT, int NOUT, bool RELU, bool OUTBF>
__global__ __launch_bounds__(256)
void mfma_gemm_kernel(const unsigned short* __restrict__ meanb,
                      const unsigned short* __restrict__ h,
                      const unsigned short* __restrict__ wfrag,
                      const float* __restrict__ bias,
                      void* __restrict__ out_) {
    const int lane = threadIdx.x & 63;
    const int wave = threadIdx.x >> 6;
    const int quad = lane >> 4;
    const int nn   = lane & 15;
    const int base = blockIdx.x * 128 + wave * 32;

    const int n0 = base + nn;
    const int n1 = base + 16 + nn;
    const size_t r0 = (size_t)min(n0, N_NODES - 1) * F;
    const size_t r1 = (size_t)min(n1, N_NODES - 1) * F;

    v4f acc[MT][2];
    #pragma unroll
    for (int mt = 0; mt < MT; ++mt) { acc[mt][0] = (v4f)0.f; acc[mt][1] = (v4f)0.f; }

    #pragma unroll
    for (int kt = 0; kt < 8; ++kt) {
        const unsigned short* B = (kt < 4) ? meanb : h;
        const int koff = (kt & 3) * 32 + quad * 8;
        v8s b0 = *(const v8s*)(B + r0 + koff);
        v8s b1 = *(const v8s*)(B + r1 + koff);
        #pragma unroll
        for (int mt = 0; mt < MT; ++mt) {
            v8s a = *(const v8s*)(wfrag + ((size_t)(mt * 8 + kt) * 64 + lane) * 8);
            acc[mt][0] = __builtin_amdgcn_mfma_f32_16x16x32_bf16(a, b0, acc[mt][0], 0, 0, 0);
            acc[mt][1] = __builtin_amdgcn_mfma_f32_16x16x32_bf16(a, b1, acc[mt][1], 0, 0, 0);
        }
    }

    #pragma unroll
    for (int mt = 0; mt < MT; ++mt) {
        const int m0 = mt * 16 + quad * 4;
        #pragma unroll
        for (int nt = 0; nt < 2; ++nt) {
            const int node = base + nt * 16 + nn;
            if (node >= N_NODES) continue;
            v4f a = acc[mt][nt];
            if (OUTBF) {
                const float4 bb = *(const float4*)(bias + m0);
                float x0 = a[0] + bb.x, x1 = a[1] + bb.y, x2 = a[2] + bb.z, x3 = a[3] + bb.w;
                if (RELU) {
                    x0 = fmaxf(x0, 0.f); x1 = fmaxf(x1, 0.f);
                    x2 = fmaxf(x2, 0.f); x3 = fmaxf(x3, 0.f);
                }
                uint2 o;
                o.x = f2bf(x0) | (f2bf(x1) << 16);
                o.y = f2bf(x2) | (f2bf(x3) << 16);
                *(uint2*)((unsigned short*)out_ + (size_t)node * F + m0) = o;
            } else {
                float* out = (float*)out_;
                #pragma unroll
                for (int r = 0; r < 4; ++r) {
                    int m = m0 + r;
                    if (m < NOUT) {
                        float v = a[r] + bias[m];
                        if (RELU) v = fmaxf(v, 0.f);
                        out[(size_t)node * NOUT + m] = v;
                    }
                }
            }
        }
    }
}

// ---------------- launch ----------------

extern "C" void kernel_launch(void* const* d_in, const int* in_sizes, int n_in,
                              void* d_out, int out_size, void* d_ws, size_t ws_size,
                              hipStream_t stream) {
    const float* embed = (const float*)d_in[0];
    const float* Ws0   = (const float*)d_in[1];
    const float* Wn0   = (const float*)d_in[2];
    const float* b0    = (const float*)d_in[3];
    const float* Ws1   = (const float*)d_in[4];
    const float* Wn1   = (const float*)d_in[5];
    const float* b1    = (const float*)d_in[6];
    const float* Ws2   = (const float*)d_in[7];
    const float* Wn2   = (const float*)d_in[8];
    const float* b2    = (const float*)d_in[9];
    const int* input_nodes = (const int*)d_in[10];
    const int* src     = (const int*)d_in[11];
    const int* dst     = (const int*)d_in[12];
    float* out = (float*)d_out;

    char* ws = (char*)d_ws;
    size_t off = 0;
    auto alloc = [&](size_t bytes) -> void* {
        void* p = ws + off;
        off += (bytes + 255) & ~(size_t)255;
        return p;
    };
    int*            cnt      = (int*)           alloc(sizeof(int) * N_NODES);
    int*            hist     = (int*)           alloc(sizeof(int) * M_CELLS);
    int*            offs     = (int*)           alloc(sizeof(int) * (M_CELLS + 8));
    int*            cursor   = (int*)           alloc(sizeof(int) * M_CELLS);
    int*            blk_sums = (int*)           alloc(sizeof(int) * 128);
    uint32*         pair     = (uint32*)        alloc(sizeof(uint32) * N_EDGES);
    unsigned short* h_a      = (unsigned short*)alloc(2 * (size_t)N_NODES * F);
    unsigned short* h_b      = (unsigned short*)alloc(2 * (size_t)N_NODES * F);
    unsigned short* meanb    = (unsigned short*)alloc(2 * (size_t)N_NODES * F);
    unsigned short* wf0      = (unsigned short*)alloc(2 * 64 * 512);
    unsigned short* wf1      = (unsigned short*)alloc(2 * 64 * 512);
    unsigned short* wf2      = (unsigned short*)alloc(2 * 24 * 512);
    (void)ws_size; (void)n_in; (void)in_sizes; (void)out_size;

    hipMemsetAsync(cnt,  0, sizeof(int) * N_NODES, stream);
    hipMemsetAsync(hist, 0, sizeof(int) * M_CELLS, stream);

    histcnt_kernel<<<NEB, 256, 0, stream>>>(dst, src, cnt, hist);
    scanA_kernel<<<SCANV_B, 1024, 0, stream>>>(hist, blk_sums);
    scanB_kernel<<<1, 128, 0, stream>>>(blk_sums, offs);
    scanC_kernel<<<SCANV_B, 1024, 0, stream>>>(hist, blk_sums, offs, cursor);
    scatter_kernel<<<NEB, 256, 0, stream>>>(dst, src, cursor, pair);

    pack_w_kernel<<<64, 64, 0, stream>>>(Wn0, Ws0, F, wf0);
    pack_w_kernel<<<64, 64, 0, stream>>>(Wn1, Ws1, F, wf1);
    pack_w_kernel<<<24, 64, 0, stream>>>(Wn2, Ws2, N_CLASSES, wf2);

    gather_embed_kernel<<<(N_NODES * (F / 4) + 255) / 256, 256, 0, stream>>>(embed, input_nodes, h_a);

    const int GEMM_B = (N_NODES + 127) / 128;

    // layer 0: h_a -> h_b
    agg_push_kernel<<<NB, 512, 0, stream>>>(h_a, pair, offs, cnt, meanb);
    mfma_gemm_kernel<8, F, true, true><<<GEMM_B, 256, 0, stream>>>(meanb, h_a, wf0, b0, h_b);
    // layer 1: h_b -> h_a
    agg_push_kernel<<<NB, 512, 0, stream>>>(h_b, pair, offs, cnt, meanb);
    mfma_gemm_kernel<8, F, true, true><<<GEMM_B, 256, 0, stream>>>(meanb, h_b, wf1, b1, h_a);
    // layer 2: h_a -> out (47 classes, no relu, fp32 out)
    agg_push_kernel<<<NB, 512, 0, stream>>>(h_a, pair, offs, cnt, meanb);
    mfma_gemm_kernel<3, N_CLASSES, false, false><<<GEMM_B, 256, 0, stream>>>(meanb, h_a, wf2, b2, out);
}

// Round 7
// 599.498 us; speedup vs baseline: 7.3947x; 7.3947x over previous
//
#include <hip/hip_runtime.h>

#define N_NODES   100000
#define N_EDGES   1600000
#define F         128
#define N_CLASSES 47
#define SCAN_B    98   // ceil(N_NODES / 1024)

typedef unsigned int uint32;

typedef short  v8s __attribute__((ext_vector_type(8)));   // 8 x bf16 (MFMA A/B frag)
typedef float  v4f __attribute__((ext_vector_type(4)));   // MFMA C/D frag

// bf16 helpers (RNE)
__device__ __forceinline__ uint32 f2bf(float f) {
    uint32 u = __float_as_uint(f);
    return (u + 0x7FFFu + ((u >> 16) & 1u)) >> 16;
}
__device__ __forceinline__ float bfl(uint32 u) { return __uint_as_float(u << 16); }
__device__ __forceinline__ float bfh(uint32 u) { return __uint_as_float(u & 0xFFFF0000u); }

// ---------------- CSR build ----------------

__global__ void count_kernel(const int* __restrict__ dst, int* __restrict__ cnt) {
    int e = blockIdx.x * blockDim.x + threadIdx.x;
    if (e < N_EDGES) atomicAdd(&cnt[dst[e]], 1);
}

__global__ void scan1_kernel(const int* __restrict__ cnt, int* __restrict__ blk_sums) {
    __shared__ int red[1024];
    int t = threadIdx.x;
    int i = blockIdx.x * 1024 + t;
    red[t] = (i < N_NODES) ? cnt[i] : 0;
    __syncthreads();
    #pragma unroll
    for (int off = 512; off > 0; off >>= 1) {
        if (t < off) red[t] += red[t + off];
        __syncthreads();
    }
    if (t == 0) blk_sums[blockIdx.x] = red[0];
}

__global__ void scan2_kernel(int* __restrict__ blk_sums, int* __restrict__ row_ptr) {
    __shared__ int s[128];
    int t = threadIdx.x;
    int v = (t < SCAN_B) ? blk_sums[t] : 0;
    s[t] = v;
    __syncthreads();
    #pragma unroll
    for (int off = 1; off < 128; off <<= 1) {
        int add = (t >= off) ? s[t - off] : 0;
        __syncthreads();
        s[t] += add;
        __syncthreads();
    }
    if (t < SCAN_B) blk_sums[t] = s[t] - v;     // exclusive offset
    if (t == SCAN_B - 1) row_ptr[N_NODES] = s[t];
}

__global__ void scan3_kernel(const int* __restrict__ cnt, const int* __restrict__ blk_offs,
                             int* __restrict__ row_ptr, float* __restrict__ rdeg) {
    __shared__ int s[1024];
    int t = threadIdx.x;
    int i = blockIdx.x * 1024 + t;
    int c = (i < N_NODES) ? cnt[i] : 0;
    s[t] = c;
    __syncthreads();
    #pragma unroll
    for (int off = 1; off < 1024; off <<= 1) {
        int add = (t >= off) ? s[t - off] : 0;
        __syncthreads();
        s[t] += add;
        __syncthreads();
    }
    if (i < N_NODES) {
        row_ptr[i] = s[t] - c + blk_offs[blockIdx.x];
        rdeg[i] = 1.0f / (float)max(c, 1);
    }
}

// XCD-grouped fill: group g = blockIdx&7 handles dst in [g*12500,(g+1)*12500).
// All writes to a col/fill region come from one XCD's L2 (round-robin
// heuristic) -> partial lines merge in cache, ~no write amplification.
// dst re-read 8x but L3-resident.

__global__ void fill_kernel(const int* __restrict__ src, const int* __restrict__ dst,
                            const int* __restrict__ row_ptr, int* __restrict__ fillc,
                            int* __restrict__ col) {
    const int g  = blockIdx.x & 7;
    const int bi = blockIdx.x >> 3;
    const int nt = (gridDim.x >> 3) * 256;
    for (int e = bi * 256 + threadIdx.x; e < N_EDGES; e += nt) {
        int d = dst[e];
        if (d / 12500 == g) {
            int p = row_ptr[d] + atomicAdd(&fillc[d], 1);
            col[p] = src[e];
        }
    }
}

// ---------------- weight pre-pack: fp32 Wn/Ws -> bf16 MFMA A-frags ----------------
// Wcat[k][m], k in [0,256): k<128 -> Wn[k][m], else Ws[k-128][m].
// A-frag (16x16x32): lane L holds A[m = L&15][k = (L>>4)*8 + j], j=0..7.

__global__ void pack_w_kernel(const float* __restrict__ Wn, const float* __restrict__ Ws,
                              int nout, unsigned short* __restrict__ wfrag) {
    int tile = blockIdx.x;           // mt*8 + kt
    int kt   = tile & 7;
    int mt   = tile >> 3;
    int lane = threadIdx.x;          // 64
    int quad = lane >> 4;
    int m    = mt * 16 + (lane & 15);
    uint32 packed[4];
    #pragma unroll
    for (int jj = 0; jj < 4; ++jj) {
        uint32 lo = 0, hi = 0;
        #pragma unroll
        for (int b = 0; b < 2; ++b) {
            int j = jj * 2 + b;
            int k = kt * 32 + quad * 8 + j;
            float w = 0.f;
            if (m < nout) w = (k < F) ? Wn[(size_t)k * nout + m] : Ws[(size_t)(k - F) * nout + m];
            if (b == 0) lo = f2bf(w); else hi = f2bf(w);
        }
        packed[jj] = lo | (hi << 16);
    }
    uint4 o = make_uint4(packed[0], packed[1], packed[2], packed[3]);
    *(uint4*)(wfrag + ((size_t)tile * 64 + lane) * 8) = o;
}

// ---------------- embedding gather: fp32 embed -> bf16 h ----------------

__global__ void gather_embed_kernel(const float* __restrict__ embed,
                                    const int* __restrict__ idx,
                                    unsigned short* __restrict__ h) {
    int i = blockIdx.x * blockDim.x + threadIdx.x;
    const int TOTAL = N_NODES * (F / 4);
    if (i < TOTAL) {
        int node = i >> 5;
        int c4 = i & 31;
        float4 v = ((const float4*)(embed + (size_t)idx[node] * F))[c4];
        uint2 o;
        o.x = f2bf(v.x) | (f2bf(v.y) << 16);
        o.y = f2bf(v.z) | (f2bf(v.w) << 16);
        ((uint2*)(h + (size_t)node * F))[c4] = o;
    }
}

// ---------------- pull aggregation (bf16 h -> bf16 mean, fp32 accum) ----------------
// one wave per node; lane handles 2 feats; 4 independent gathers in flight.

__global__ void aggregate_kernel(const unsigned short* __restrict__ h,
                                 const int* __restrict__ row_ptr,
                                 const int* __restrict__ col,
                                 const float* __restrict__ rdeg,
                                 unsigned short* __restrict__ mean) {
    int wave = threadIdx.x >> 6;
    int lane = threadIdx.x & 63;
    int v = blockIdx.x * 4 + wave;
    if (v >= N_NODES) return;
    const uint32* hp = (const uint32*)h;   // 64 uints per row
    int beg = row_ptr[v], end = row_ptr[v + 1];
    float ax = 0.f, ay = 0.f;
    int p = beg;
    for (; p + 4 <= end; p += 4) {
        int u0 = col[p], u1 = col[p + 1], u2 = col[p + 2], u3 = col[p + 3];
        uint32 x0 = hp[(size_t)u0 * 64 + lane];
        uint32 x1 = hp[(size_t)u1 * 64 + lane];
        uint32 x2 = hp[(size_t)u2 * 64 + lane];
        uint32 x3 = hp[(size_t)u3 * 64 + lane];
        ax += bfl(x0) + bfl(x1) + bfl(x2) + bfl(x3);
        ay += bfh(x0) + bfh(x1) + bfh(x2) + bfh(x3);
    }
    for (; p < end; ++p) {
        uint32 x = hp[(size_t)col[p] * 64 + lane];
        ax += bfl(x);
        ay += bfh(x);
    }
    float r = rdeg[v];
    ((uint32*)mean)[(size_t)v * 64 + lane] = f2bf(ax * r) | (f2bf(ay * r) << 16);
}

// ---------------- MFMA GEMM: out = [mean|h] @ Wcat + b (+relu) ----------------
// m = out-feature, n = node. A = pre-packed W frags (L1-broadcast), B = node rows
// loaded straight from global. No LDS.

template<int MT, int NOUT, bool RELU, bool OUTBF>
__global__ __launch_bounds__(256)
void mfma_gemm_kernel(const unsigned short* __restrict__ meanb,
                      const unsigned short* __restrict__ h,
                      const unsigned short* __restrict__ wfrag,
                      const float* __restrict__ bias,
                      void* __restrict__ out_) {
    const int lane = threadIdx.x & 63;
    const int wave = threadIdx.x >> 6;
    const int quad = lane >> 4;
    const int nn   = lane & 15;
    const int base = blockIdx.x * 128 + wave * 32;

    const int n0 = base + nn;
    const int n1 = base + 16 + nn;
    const size_t r0 = (size_t)min(n0, N_NODES - 1) * F;
    const size_t r1 = (size_t)min(n1, N_NODES - 1) * F;

    v4f acc[MT][2];
    #pragma unroll
    for (int mt = 0; mt < MT; ++mt) { acc[mt][0] = (v4f)0.f; acc[mt][1] = (v4f)0.f; }

    #pragma unroll
    for (int kt = 0; kt < 8; ++kt) {
        const unsigned short* B = (kt < 4) ? meanb : h;
        const int koff = (kt & 3) * 32 + quad * 8;
        v8s b0 = *(const v8s*)(B + r0 + koff);
        v8s b1 = *(const v8s*)(B + r1 + koff);
        #pragma unroll
        for (int mt = 0; mt < MT; ++mt) {
            v8s a = *(const v8s*)(wfrag + ((size_t)(mt * 8 + kt) * 64 + lane) * 8);
            acc[mt][0] = __builtin_amdgcn_mfma_f32_16x16x32_bf16(a, b0, acc[mt][0], 0, 0, 0);
            acc[mt][1] = __builtin_amdgcn_mfma_f32_16x16x32_bf16(a, b1, acc[mt][1], 0, 0, 0);
        }
    }

    #pragma unroll
    for (int mt = 0; mt < MT; ++mt) {
        const int m0 = mt * 16 + quad * 4;
        #pragma unroll
        for (int nt = 0; nt < 2; ++nt) {
            const int node = base + nt * 16 + nn;
            if (node >= N_NODES) continue;
            v4f a = acc[mt][nt];
            if (OUTBF) {
                const float4 bb = *(const float4*)(bias + m0);
                float x0 = a[0] + bb.x, x1 = a[1] + bb.y, x2 = a[2] + bb.z, x3 = a[3] + bb.w;
                if (RELU) {
                    x0 = fmaxf(x0, 0.f); x1 = fmaxf(x1, 0.f);
                    x2 = fmaxf(x2, 0.f); x3 = fmaxf(x3, 0.f);
                }
                uint2 o;
                o.x = f2bf(x0) | (f2bf(x1) << 16);
                o.y = f2bf(x2) | (f2bf(x3) << 16);
                *(uint2*)((unsigned short*)out_ + (size_t)node * F + m0) = o;
            } else {
                float* out = (float*)out_;
                #pragma unroll
                for (int r = 0; r < 4; ++r) {
                    int m = m0 + r;
                    if (m < NOUT) {
                        float v = a[r] + bias[m];
                        if (RELU) v = fmaxf(v, 0.f);
                        out[(size_t)node * NOUT + m] = v;
                    }
                }
            }
        }
    }
}

// ---------------- launch ----------------

extern "C" void kernel_launch(void* const* d_in, const int* in_sizes, int n_in,
                              void* d_out, int out_size, void* d_ws, size_t ws_size,
                              hipStream_t stream) {
    const float* embed = (const float*)d_in[0];
    const float* Ws0   = (const float*)d_in[1];
    const float* Wn0   = (const float*)d_in[2];
    const float* b0    = (const float*)d_in[3];
    const float* Ws1   = (const float*)d_in[4];
    const float* Wn1   = (const float*)d_in[5];
    const float* b1    = (const float*)d_in[6];
    const float* Ws2   = (const float*)d_in[7];
    const float* Wn2   = (const float*)d_in[8];
    const float* b2    = (const float*)d_in[9];
    const int* input_nodes = (const int*)d_in[10];
    const int* src     = (const int*)d_in[11];
    const int* dst     = (const int*)d_in[12];
    float* out = (float*)d_out;

    char* ws = (char*)d_ws;
    size_t off = 0;
    auto alloc = [&](size_t bytes) -> void* {
        void* p = ws + off;
        off += (bytes + 255) & ~(size_t)255;
        return p;
    };
    int*            cnt      = (int*)           alloc(sizeof(int)   * N_NODES);
    int*            fillc    = (int*)           alloc(sizeof(int)   * N_NODES);
    int*            row_ptr  = (int*)           alloc(sizeof(int)   * (N_NODES + 1));
    float*          rdeg     = (float*)         alloc(sizeof(float) * N_NODES);
    int*            col      = (int*)           alloc(sizeof(int)   * N_EDGES);
    int*            blk_sums = (int*)           alloc(sizeof(int)   * 128);
    unsigned short* h_a      = (unsigned short*)alloc(2 * (size_t)N_NODES * F);
    unsigned short* h_b      = (unsigned short*)alloc(2 * (size_t)N_NODES * F);
    unsigned short* meanb    = (unsigned short*)alloc(2 * (size_t)N_NODES * F);
    unsigned short* wf0      = (unsigned short*)alloc(2 * 64 * 512);
    unsigned short* wf1      = (unsigned short*)alloc(2 * 64 * 512);
    unsigned short* wf2      = (unsigned short*)alloc(2 * 24 * 512);
    (void)ws_size; (void)n_in; (void)in_sizes; (void)out_size;

    hipMemsetAsync(cnt,   0, sizeof(int) * N_NODES, stream);
    hipMemsetAsync(fillc, 0, sizeof(int) * N_NODES, stream);

    const int EB = (N_EDGES + 255) / 256;
    count_kernel<<<EB, 256, 0, stream>>>(dst, cnt);
    scan1_kernel<<<SCAN_B, 1024, 0, stream>>>(cnt, blk_sums);
    scan2_kernel<<<1, 128, 0, stream>>>(blk_sums, row_ptr);
    scan3_kernel<<<SCAN_B, 1024, 0, stream>>>(cnt, blk_sums, row_ptr, rdeg);
    fill_kernel<<<5000, 256, 0, stream>>>(src, dst, row_ptr, fillc, col);

    pack_w_kernel<<<64, 64, 0, stream>>>(Wn0, Ws0, F, wf0);
    pack_w_kernel<<<64, 64, 0, stream>>>(Wn1, Ws1, F, wf1);
    pack_w_kernel<<<24, 64, 0, stream>>>(Wn2, Ws2, N_CLASSES, wf2);

    gather_embed_kernel<<<(N_NODES * (F / 4) + 255) / 256, 256, 0, stream>>>(embed, input_nodes, h_a);

    const int AGG_B  = (N_NODES + 3) / 4;
    const int GEMM_B = (N_NODES + 127) / 128;

    // layer 0: h_a -> h_b
    aggregate_kernel<<<AGG_B, 256, 0, stream>>>(h_a, row_ptr, col, rdeg, meanb);
    mfma_gemm_kernel<8, F, true, true><<<GEMM_B, 256, 0, stream>>>(meanb, h_a, wf0, b0, h_b);
    // layer 1: h_b -> h_a
    aggregate_kernel<<<AGG_B, 256, 0, stream>>>(h_b, row_ptr, col, rdeg, meanb);
    mfma_gemm_kernel<8, F, true, true><<<GEMM_B, 256, 0, stream>>>(meanb, h_b, wf1, b1, h_a);
    // layer 2: h_a -> out (47 classes, no relu, fp32 out)
    aggregate_kernel<<<AGG_B, 256, 0, stream>>>(h_a, row_ptr, col, rdeg, meanb);
    mfma_gemm_kernel<3, N_CLASSES, false, false><<<GEMM_B, 256, 0, stream>>>(meanb, h_a, wf2, b2, out);
}

// Round 8
// 558.070 us; speedup vs baseline: 7.9436x; 1.0742x over previous
//
#include <hip/hip_runtime.h>

#define N_NODES   100000
#define N_EDGES   1600000
#define F         128
#define N_CLASSES 47
#define SCAN_B    98   // ceil(N_NODES / 1024)

typedef unsigned int uint32;

typedef short  v8s __attribute__((ext_vector_type(8)));   // 8 x bf16 (MFMA A/B frag)
typedef float  v4f __attribute__((ext_vector_type(4)));   // MFMA C/D frag

// bf16 helpers (RNE)
__device__ __forceinline__ uint32 f2bf(float f) {
    uint32 u = __float_as_uint(f);
    return (u + 0x7FFFu + ((u >> 16) & 1u)) >> 16;
}
__device__ __forceinline__ float bfl(uint32 u) { return __uint_as_float(u << 16); }
__device__ __forceinline__ float bfh(uint32 u) { return __uint_as_float(u & 0xFFFF0000u); }

// ---------------- CSR build ----------------

__global__ void count_kernel(const int* __restrict__ dst, int* __restrict__ cnt) {
    int e = blockIdx.x * blockDim.x + threadIdx.x;
    if (e < N_EDGES) atomicAdd(&cnt[dst[e]], 1);
}

__global__ void scan1_kernel(const int* __restrict__ cnt, int* __restrict__ blk_sums) {
    __shared__ int red[1024];
    int t = threadIdx.x;
    int i = blockIdx.x * 1024 + t;
    red[t] = (i < N_NODES) ? cnt[i] : 0;
    __syncthreads();
    #pragma unroll
    for (int off = 512; off > 0; off >>= 1) {
        if (t < off) red[t] += red[t + off];
        __syncthreads();
    }
    if (t == 0) blk_sums[blockIdx.x] = red[0];
}

__global__ void scan2_kernel(int* __restrict__ blk_sums, int* __restrict__ row_ptr) {
    __shared__ int s[128];
    int t = threadIdx.x;
    int v = (t < SCAN_B) ? blk_sums[t] : 0;
    s[t] = v;
    __syncthreads();
    #pragma unroll
    for (int off = 1; off < 128; off <<= 1) {
        int add = (t >= off) ? s[t - off] : 0;
        __syncthreads();
        s[t] += add;
        __syncthreads();
    }
    if (t < SCAN_B) blk_sums[t] = s[t] - v;     // exclusive offset
    if (t == SCAN_B - 1) row_ptr[N_NODES] = s[t];
}

__global__ void scan3_kernel(const int* __restrict__ cnt, const int* __restrict__ blk_offs,
                             int* __restrict__ row_ptr, float* __restrict__ rdeg) {
    __shared__ int s[1024];
    int t = threadIdx.x;
    int i = blockIdx.x * 1024 + t;
    int c = (i < N_NODES) ? cnt[i] : 0;
    s[t] = c;
    __syncthreads();
    #pragma unroll
    for (int off = 1; off < 1024; off <<= 1) {
        int add = (t >= off) ? s[t - off] : 0;
        __syncthreads();
        s[t] += add;
        __syncthreads();
    }
    if (i < N_NODES) {
        row_ptr[i] = s[t] - c + blk_offs[blockIdx.x];
        rdeg[i] = 1.0f / (float)max(c, 1);
    }
}

// XCD-grouped fill: group g = blockIdx&7 handles dst in [g*12500,(g+1)*12500).
// All writes to a col region come from one XCD's L2 -> dirty lines merge.

__global__ void fill_kernel(const int* __restrict__ src, const int* __restrict__ dst,
                            const int* __restrict__ row_ptr, int* __restrict__ fillc,
                            int* __restrict__ col) {
    const int g  = blockIdx.x & 7;
    const int bi = blockIdx.x >> 3;
    const int nt = (gridDim.x >> 3) * 256;
    for (int e = bi * 256 + threadIdx.x; e < N_EDGES; e += nt) {
        int d = dst[e];
        if (d / 12500 == g) {
            int p = row_ptr[d] + atomicAdd(&fillc[d], 1);
            col[p] = src[e];
        }
    }
}

// ---------------- weight pre-pack: fp32 Wn/Ws -> bf16 MFMA A-frags ----------------

__global__ void pack_w_kernel(const float* __restrict__ Wn, const float* __restrict__ Ws,
                              int nout, unsigned short* __restrict__ wfrag) {
    int tile = blockIdx.x;           // mt*8 + kt
    int kt   = tile & 7;
    int mt   = tile >> 3;
    int lane = threadIdx.x;          // 64
    int quad = lane >> 4;
    int m    = mt * 16 + (lane & 15);
    uint32 packed[4];
    #pragma unroll
    for (int jj = 0; jj < 4; ++jj) {
        uint32 lo = 0, hi = 0;
        #pragma unroll
        for (int b = 0; b < 2; ++b) {
            int j = jj * 2 + b;
            int k = kt * 32 + quad * 8 + j;
            float w = 0.f;
            if (m < nout) w = (k < F) ? Wn[(size_t)k * nout + m] : Ws[(size_t)(k - F) * nout + m];
            if (b == 0) lo = f2bf(w); else hi = f2bf(w);
        }
        packed[jj] = lo | (hi << 16);
    }
    uint4 o = make_uint4(packed[0], packed[1], packed[2], packed[3]);
    *(uint4*)(wfrag + ((size_t)tile * 64 + lane) * 8) = o;
}

// ---------------- embedding gather: fp32 embed -> bf16 h ----------------

__global__ void gather_embed_kernel(const float* __restrict__ embed,
                                    const int* __restrict__ idx,
                                    unsigned short* __restrict__ h) {
    int i = blockIdx.x * blockDim.x + threadIdx.x;
    const int TOTAL = N_NODES * (F / 4);
    if (i < TOTAL) {
        int node = i >> 5;
        int c4 = i & 31;
        float4 v = ((const float4*)(embed + (size_t)idx[node] * F))[c4];
        uint2 o;
        o.x = f2bf(v.x) | (f2bf(v.y) << 16);
        o.y = f2bf(v.z) | (f2bf(v.w) << 16);
        ((uint2*)(h + (size_t)node * F))[c4] = o;
    }
}

// ---------------- pull aggregation (bf16 h -> bf16 mean, fp32 accum) ----------------
// one wave per node; 4 sub-groups x 16 lanes; each sub-group loads a FULL
// 256B neighbor row as uint4 (16B/lane) -> 4 edges per iter in one load
// instruction (1KB/wave in flight per iter). col prefetched one iter ahead.
// Epilogue: shfl_xor(16,32) butterfly merges the 4 sub-group partials.

__global__ void aggregate_kernel(const unsigned short* __restrict__ h,
                                 const int* __restrict__ row_ptr,
                                 const int* __restrict__ col,
                                 const float* __restrict__ rdeg,
                                 unsigned short* __restrict__ mean) {
    const int wave = threadIdx.x >> 6;
    const int lane = threadIdx.x & 63;
    const int sub  = lane >> 4;          // which of 4 edges per iter
    const int li   = lane & 15;          // 16B slot within the row
    const int v    = blockIdx.x * 4 + wave;
    if (v >= N_NODES) return;

    const uint4* hp4 = (const uint4*)h;  // 16 uint4 per 256B row
    const int beg = row_ptr[v], end = row_ptr[v + 1];

    float a0 = 0.f, a1 = 0.f, a2 = 0.f, a3 = 0.f;
    float a4 = 0.f, a5 = 0.f, a6 = 0.f, a7 = 0.f;

    int p = beg;
    int u = col[min(p + sub, N_EDGES - 1)];   // prefetch (clamped, safe)
    #pragma unroll 2
    for (; p + 4 <= end; p += 4) {
        int un = col[min(p + 4 + sub, N_EDGES - 1)];
        uint4 x = hp4[(size_t)u * 16 + li];
        a0 += bfl(x.x); a1 += bfh(x.x);
        a2 += bfl(x.y); a3 += bfh(x.y);
        a4 += bfl(x.z); a5 += bfh(x.z);
        a6 += bfl(x.w); a7 += bfh(x.w);
        u = un;
    }
    if (p + sub < end) {                      // tail (u already prefetched)
        uint4 x = hp4[(size_t)u * 16 + li];
        a0 += bfl(x.x); a1 += bfh(x.x);
        a2 += bfl(x.y); a3 += bfh(x.y);
        a4 += bfl(x.z); a5 += bfh(x.z);
        a6 += bfl(x.w); a7 += bfh(x.w);
    }

    // merge the 4 sub-group partials (lanes with same li)
    #pragma unroll
    for (int m = 16; m <= 32; m <<= 1) {
        a0 += __shfl_xor(a0, m, 64);
        a1 += __shfl_xor(a1, m, 64);
        a2 += __shfl_xor(a2, m, 64);
        a3 += __shfl_xor(a3, m, 64);
        a4 += __shfl_xor(a4, m, 64);
        a5 += __shfl_xor(a5, m, 64);
        a6 += __shfl_xor(a6, m, 64);
        a7 += __shfl_xor(a7, m, 64);
    }

    if (sub == 0) {
        const float r = rdeg[v];
        uint4 o;
        o.x = f2bf(a0 * r) | (f2bf(a1 * r) << 16);
        o.y = f2bf(a2 * r) | (f2bf(a3 * r) << 16);
        o.z = f2bf(a4 * r) | (f2bf(a5 * r) << 16);
        o.w = f2bf(a6 * r) | (f2bf(a7 * r) << 16);
        ((uint4*)mean)[(size_t)v * 16 + li] = o;
    }
}

// ---------------- MFMA GEMM: out = [mean|h] @ Wcat + b (+relu) ----------------

template<int MT, int NOUT, bool RELU, bool OUTBF>
__global__ __launch_bounds__(256)
void mfma_gemm_kernel(const unsigned short* __restrict__ meanb,
                      const unsigned short* __restrict__ h,
                      const unsigned short* __restrict__ wfrag,
                      const float* __restrict__ bias,
                      void* __restrict__ out_) {
    const int lane = threadIdx.x & 63;
    const int wave = threadIdx.x >> 6;
    const int quad = lane >> 4;
    const int nn   = lane & 15;
    const int base = blockIdx.x * 128 + wave * 32;

    const int n0 = base + nn;
    const int n1 = base + 16 + nn;
    const size_t r0 = (size_t)min(n0, N_NODES - 1) * F;
    const size_t r1 = (size_t)min(n1, N_NODES - 1) * F;

    v4f acc[MT][2];
    #pragma unroll
    for (int mt = 0; mt < MT; ++mt) { acc[mt][0] = (v4f)0.f; acc[mt][1] = (v4f)0.f; }

    #pragma unroll
    for (int kt = 0; kt < 8; ++kt) {
        const unsigned short* B = (kt < 4) ? meanb : h;
        const int koff = (kt & 3) * 32 + quad * 8;
        v8s b0 = *(const v8s*)(B + r0 + koff);
        v8s b1 = *(const v8s*)(B + r1 + koff);
        #pragma unroll
        for (int mt = 0; mt < MT; ++mt) {
            v8s a = *(const v8s*)(wfrag + ((size_t)(mt * 8 + kt) * 64 + lane) * 8);
            acc[mt][0] = __builtin_amdgcn_mfma_f32_16x16x32_bf16(a, b0, acc[mt][0], 0, 0, 0);
            acc[mt][1] = __builtin_amdgcn_mfma_f32_16x16x32_bf16(a, b1, acc[mt][1], 0, 0, 0);
        }
    }

    #pragma unroll
    for (int mt = 0; mt < MT; ++mt) {
        const int m0 = mt * 16 + quad * 4;
        #pragma unroll
        for (int nt = 0; nt < 2; ++nt) {
            const int node = base + nt * 16 + nn;
            if (node >= N_NODES) continue;
            v4f a = acc[mt][nt];
            if (OUTBF) {
                const float4 bb = *(const float4*)(bias + m0);
                float x0 = a[0] + bb.x, x1 = a[1] + bb.y, x2 = a[2] + bb.z, x3 = a[3] + bb.w;
                if (RELU) {
                    x0 = fmaxf(x0, 0.f); x1 = fmaxf(x1, 0.f);
                    x2 = fmaxf(x2, 0.f); x3 = fmaxf(x3, 0.f);
                }
                uint2 o;
                o.x = f2bf(x0) | (f2bf(x1) << 16);
                o.y = f2bf(x2) | (f2bf(x3) << 16);
                *(uint2*)((unsigned short*)out_ + (size_t)node * F + m0) = o;
            } else {
                float* out = (float*)out_;
                #pragma unroll
                for (int r = 0; r < 4; ++r) {
                    int m = m0 + r;
                    if (m < NOUT) {
                        float v = a[r] + bias[m];
                        if (RELU) v = fmaxf(v, 0.f);
                        out[(size_t)node * NOUT + m] = v;
                    }
                }
            }
        }
    }
}

// ---------------- launch ----------------

extern "C" void kernel_launch(void* const* d_in, const int* in_sizes, int n_in,
                              void* d_out, int out_size, void* d_ws, size_t ws_size,
                              hipStream_t stream) {
    const float* embed = (const float*)d_in[0];
    const float* Ws0   = (const float*)d_in[1];
    const float* Wn0   = (const float*)d_in[2];
    const float* b0    = (const float*)d_in[3];
    const float* Ws1   = (const float*)d_in[4];
    const float* Wn1   = (const float*)d_in[5];
    const float* b1    = (const float*)d_in[6];
    const float* Ws2   = (const float*)d_in[7];
    const float* Wn2   = (const float*)d_in[8];
    const float* b2    = (const float*)d_in[9];
    const int* input_nodes = (const int*)d_in[10];
    const int* src     = (const int*)d_in[11];
    const int* dst     = (const int*)d_in[12];
    float* out = (float*)d_out;

    char* ws = (char*)d_ws;
    size_t off = 0;
    auto alloc = [&](size_t bytes) -> void* {
        void* p = ws + off;
        off += (bytes + 255) & ~(size_t)255;
        return p;
    };
    int*            cnt      = (int*)           alloc(sizeof(int)   * N_NODES);
    int*            fillc    = (int*)           alloc(sizeof(int)   * N_NODES);
    int*            row_ptr  = (int*)           alloc(sizeof(int)   * (N_NODES + 1));
    float*          rdeg     = (float*)         alloc(sizeof(float) * N_NODES);
    int*            col      = (int*)           alloc(sizeof(int)   * N_EDGES);
    int*            blk_sums = (int*)           alloc(sizeof(int)   * 128);
    unsigned short* h_a      = (unsigned short*)alloc(2 * (size_t)N_NODES * F);
    unsigned short* h_b      = (unsigned short*)alloc(2 * (size_t)N_NODES * F);
    unsigned short* meanb    = (unsigned short*)alloc(2 * (size_t)N_NODES * F);
    unsigned short* wf0      = (unsigned short*)alloc(2 * 64 * 512);
    unsigned short* wf1      = (unsigned short*)alloc(2 * 64 * 512);
    unsigned short* wf2      = (unsigned short*)alloc(2 * 24 * 512);
    (void)ws_size; (void)n_in; (void)in_sizes; (void)out_size;

    hipMemsetAsync(cnt,   0, sizeof(int) * N_NODES, stream);
    hipMemsetAsync(fillc, 0, sizeof(int) * N_NODES, stream);

    const int EB = (N_EDGES + 255) / 256;
    count_kernel<<<EB, 256, 0, stream>>>(dst, cnt);
    scan1_kernel<<<SCAN_B, 1024, 0, stream>>>(cnt, blk_sums);
    scan2_kernel<<<1, 128, 0, stream>>>(blk_sums, row_ptr);
    scan3_kernel<<<SCAN_B, 1024, 0, stream>>>(cnt, blk_sums, row_ptr, rdeg);
    fill_kernel<<<5000, 256, 0, stream>>>(src, dst, row_ptr, fillc, col);

    pack_w_kernel<<<64, 64, 0, stream>>>(Wn0, Ws0, F, wf0);
    pack_w_kernel<<<64, 64, 0, stream>>>(Wn1, Ws1, F, wf1);
    pack_w_kernel<<<24, 64, 0, stream>>>(Wn2, Ws2, N_CLASSES, wf2);

    gather_embed_kernel<<<(N_NODES * (F / 4) + 255) / 256, 256, 0, stream>>>(embed, input_nodes, h_a);

    const int AGG_B  = (N_NODES + 3) / 4;
    const int GEMM_B = (N_NODES + 127) / 128;

    // layer 0: h_a -> h_b
    aggregate_kernel<<<AGG_B, 256, 0, stream>>>(h_a, row_ptr, col, rdeg, meanb);
    mfma_gemm_kernel<8, F, true, true><<<GEMM_B, 256, 0, stream>>>(meanb, h_a, wf0, b0, h_b);
    // layer 1: h_b -> h_a
    aggregate_kernel<<<AGG_B, 256, 0, stream>>>(h_b, row_ptr, col, rdeg, meanb);
    mfma_gemm_kernel<8, F, true, true><<<GEMM_B, 256, 0, stream>>>(meanb, h_b, wf1, b1, h_a);
    // layer 2: h_a -> out (47 classes, no relu, fp32 out)
    aggregate_kernel<<<AGG_B, 256, 0, stream>>>(h_a, row_ptr, col, rdeg, meanb);
    mfma_gemm_kernel<3, N_CLASSES, false, false><<<GEMM_B, 256, 0, stream>>>(meanb, h_a, wf2, b2, out);
}